// Round 6
// baseline (348.962 us; speedup 1.0000x reference)
//
#include <hip/hip_runtime.h>

// ---------------------------------------------------------------------------
// VoxMLP round 12: K=128 MX-scaled fp8 MFMA (unit scales) — 264 -> 82 MFMAs.
//   Round 11 accounting: matrix pipe = 42% of voxmlp cycles, MFMA count is
//   minimal for K=32 instructions -> switch MLP to
//   __builtin_amdgcn_mfma_scale_f32_16x16x128_f8f6f4 (fp8 e4m3, scale=0x7F
//   = 1.0, numerically identical). Per-lane B-fragment (32 contiguous k) ==
//   the 8 packed dwords a lane already produces, so with hidperm2
//   (k -> unit 16*((k&31)>>2) + 4*(k>>5) + (k&3)) the producer's v8i IS the
//   next layer's B operand. Features zero-padded to K=128, natural order.
//   Keeps: pt-inner layers, SCHED_FENCE per ut (hoisting bound), (256,5),
//   streamed pos-enc, vsin epilogue, byte-offset trilinear.
// ---------------------------------------------------------------------------

typedef __attribute__((ext_vector_type(4))) float f4;
typedef long long llg;                                        // 8 x fp8
typedef __attribute__((ext_vector_type(2))) long long llg2;   // 16 B
typedef __attribute__((ext_vector_type(8))) int v8i;          // 32 x fp8

#define MFMASC(A,B,C) \
    __builtin_amdgcn_mfma_scale_f32_16x16x128_f8f6f4((A),(B),(C),0,0,0,0x7f,0,0x7f)
#define SCHED_FENCE() __builtin_amdgcn_sched_barrier(0)

__device__ __forceinline__ float bf2f(unsigned int u) {
    union { float f; unsigned int i; } v; v.i = u << 16; return v.f;
}
__device__ __forceinline__ unsigned int pkbf(float a, float b) {
    unsigned int r;
    asm("v_cvt_pk_bf16_f32 %0, %1, %2" : "=v"(r) : "v"(a), "v"(b));
    return r;
}
__device__ __forceinline__ float vfract(float a) {
    float d; asm("v_fract_f32 %0, %1" : "=v"(d) : "v"(a)); return d;
}
__device__ __forceinline__ float vsin(float a) {
    float d; asm("v_sin_f32 %0, %1" : "=v"(d) : "v"(a)); return d;
}
__device__ __forceinline__ float gv(const float* __restrict__ g, int i, int j, int k) {
    return g[(i * 256 + j) * 256 + k];
}
// K=128 B-fragment slot k -> producing-layer unit (producer v8i == B operand)
__device__ __forceinline__ int hidperm2(int k) {
    const int q = k >> 5, m = k & 31, t = m >> 2, j = m & 3;
    return 16 * t + 4 * q + j;
}
__device__ __forceinline__ unsigned int pack8(f4 acc) {
    int d = __builtin_amdgcn_cvt_pk_fp8_f32(fmaxf(acc[0], 0.f), fmaxf(acc[1], 0.f), 0, false);
    d     = __builtin_amdgcn_cvt_pk_fp8_f32(fmaxf(acc[2], 0.f), fmaxf(acc[3], 0.f), d, true);
    return (unsigned int)d;
}
__device__ __forceinline__ v8i ldv8(const unsigned char* p) {
    union { v8i v; llg2 h[2]; } u;
    u.h[0] = *(const llg2*)(p);
    u.h[1] = *(const llg2*)(p + 16);
    return u.v;
}

// ---- d_ws layout ----
// fp8 weight A-fragments for 16x16x128 f8f6f4 (lane holds row=lane&15,
// k = kb*128 + (lane>>4)*32 + m, m=0..31):
//   byte = region + ((nt*KT + kb)*64 + lane)*32 + m
//   L0@0      (K128 feat-padded, NT=8, KT=1, 16384 B)
//   L1@16384  (K128, NT=8, KT=1)
//   L2@32768  (K128, NT=8, KT=1)
//   L3@49152  (K256: kb0=hidden, kb1=features, NT=8, KT=2, 32768 B)
//   out@81920 (K128, NT=1, KT=1, wo*2^13, 2048 B)
// shorts from 131072 (byte 262144): bf16x4 data grid (16.7M voxels * 8 B)
#define L0OFF 0
#define L1OFF 16384
#define L2OFF 32768
#define L3OFF 49152
#define OUTOFF 81920
#define WS_TOTAL 83968
#define SWZ_BLOCKS 328          // 328*256 == 83968 (one byte per thread)
#define DG_BLOCKS 8192          // 2^21 threads x 8 voxels
#define DG_OFF_SH 131072
#define WS_NEED (262144ull + 16777216ull * 8ull)
#define WO_SCALE 8192.0f
#define WO_INV   (1.0f / 8192.0f)
#define INV2PI 0.15915494309189535f

__global__ __launch_bounds__(256) void prep(
    const float* __restrict__ g,
    const float* __restrict__ w0, const float* __restrict__ w1,
    const float* __restrict__ w2, const float* __restrict__ w3,
    const float* __restrict__ wo,
    unsigned char* __restrict__ ws8, unsigned short* __restrict__ dg,
    int do_dgrid)
{
    const int bid = blockIdx.x;
    if (bid < SWZ_BLOCKS) {
        // ---------------- weight swizzle -> fp8 K=128 A-fragments ----------
        int idx = bid * 256 + threadIdx.x;
        const float* src; int base, KT;
        if (idx < 16384)      { src = w0; base = L0OFF;  KT = 1; }
        else if (idx < 32768) { src = w1; base = L1OFF;  KT = 1; }
        else if (idx < 49152) { src = w2; base = L2OFF;  KT = 1; }
        else if (idx < 81920) { src = w3; base = L3OFF;  KT = 2; }
        else                  { src = wo; base = OUTOFF; KT = 1; }
        int local = idx - base;
        int m    = local & 31;
        int lane = (local >> 5) & 63;
        int tile = local >> 11;
        int kb   = (KT == 2) ? (tile & 1) : 0;
        int nt   = (KT == 2) ? (tile >> 1) : tile;
        int k = kb * 128 + ((lane >> 4) << 5) + m;
        int n = nt * 16 + (lane & 15);
        float v = 0.0f;
        if (base == L0OFF) {                       // L0: features, natural order
            if (k < 63) v = src[k * 128 + n];
        } else if (base == L3OFF) {                // L3: hidden block + feature block
            if (kb == 0) v = src[hidperm2(k) * 128 + n];
            else { int f = k - 128; if (f < 63) v = src[(128 + f) * 128 + n]; }
        } else if (base == OUTOFF) {               // out: wo (128x3), scaled
            if (n < 3) v = src[hidperm2(k) * 3 + n] * WO_SCALE;
        } else {                                   // L1/L2: hidden units
            v = src[hidperm2(k) * 128 + n];
        }
        int p = __builtin_amdgcn_cvt_pk_fp8_f32(v, v, 0, false);
        ws8[idx] = (unsigned char)(p & 0xff);
    } else if (do_dgrid) {
        // ---------------- data grid build (8 voxels/thread) ----------------
        const int t  = (bid - SWZ_BLOCKS) * 256 + threadIdx.x;   // [0, 2^21)
        const int k0 = (t & 31) << 3;
        const int j  = (t >> 5) & 255;
        const int i  = t >> 13;
        const float* row = g + (i * 256 + j) * 256;
        const float* rxp = g + (min(i + 1, 255) * 256 + j) * 256;
        const float* rxm = g + (max(i - 1, 0)   * 256 + j) * 256;
        const float* ryp = g + (i * 256 + min(j + 1, 255)) * 256;
        const float* rym = g + (i * 256 + max(j - 1, 0))   * 256;
        float se[8], sxp[8], sxm[8], syp[8], sym[8];
        {
            f4 a = *(const f4*)(row + k0), b = *(const f4*)(row + k0 + 4);
            #pragma unroll
            for (int q = 0; q < 4; ++q) { se[q] = a[q]; se[q + 4] = b[q]; }
            a = *(const f4*)(rxp + k0); b = *(const f4*)(rxp + k0 + 4);
            #pragma unroll
            for (int q = 0; q < 4; ++q) { sxp[q] = a[q]; sxp[q + 4] = b[q]; }
            a = *(const f4*)(rxm + k0); b = *(const f4*)(rxm + k0 + 4);
            #pragma unroll
            for (int q = 0; q < 4; ++q) { sxm[q] = a[q]; sxm[q + 4] = b[q]; }
            a = *(const f4*)(ryp + k0); b = *(const f4*)(ryp + k0 + 4);
            #pragma unroll
            for (int q = 0; q < 4; ++q) { syp[q] = a[q]; syp[q + 4] = b[q]; }
            a = *(const f4*)(rym + k0); b = *(const f4*)(rym + k0 + 4);
            #pragma unroll
            for (int q = 0; q < 4; ++q) { sym[q] = a[q]; sym[q + 4] = b[q]; }
        }
        float zv[10];
        zv[0] = row[max(k0 - 1, 0)];
        #pragma unroll
        for (int q = 0; q < 8; ++q) zv[q + 1] = se[q];
        zv[9] = row[min(k0 + 8, 255)];
        unsigned int o[16];
        #pragma unroll
        for (int q = 0; q < 8; ++q) {
            o[q * 2 + 0] = pkbf(se[q], (sxp[q] - sxm[q]) * 63.75f);
            o[q * 2 + 1] = pkbf((syp[q] - sym[q]) * 63.75f, (zv[q + 2] - zv[q]) * 63.75f);
        }
        unsigned short* dst = dg + (size_t)(((i * 256 + j) * 256 + k0)) * 4;
        #pragma unroll
        for (int q = 0; q < 4; ++q)
            *(uint4*)(dst + q * 8) = *(const uint4*)(&o[q * 4]);
    }
}

// per-wave LDS (bytes): fbuf 32 rows x 144 B:
//   [0..127] fp8 features (0..62 real, 63..127 zero), [128..139] c1..c3 stash.
#define FSTRIDE_B 144
#define WV_BYTES (32 * FSTRIDE_B)    // 4608

template<bool FAST>
__global__ __launch_bounds__(256, 5) void voxmlp(
    const float* __restrict__ x, const float* __restrict__ grid,
    const unsigned char* __restrict__ ws8, const unsigned short* __restrict__ dg,
    const float* __restrict__ b0, const float* __restrict__ b1,
    const float* __restrict__ b2, const float* __restrict__ b3,
    const float* __restrict__ bo,
    float* __restrict__ out, int B)
{
    __shared__ unsigned char smem[WV_BYTES * 4];   // 18432 B

    const int lane = threadIdx.x & 63;
    const int wave = threadIdx.x >> 6;
    const int quad = lane >> 4;
    const int lm   = lane & 15;
    unsigned char* fbuf = smem + wave * WV_BYTES;

    const int pbase = blockIdx.x * 128 + wave * 32;

    // ================= Phase 1 ============================================
    const int p2   = lane & 31;
    const int role = lane >> 5;
    const int pid  = pbase + p2;

    const float px = x[pid * 3 + 0];
    const float py = x[pid * 3 + 1];
    const float pz = x[pid * 3 + 2];

    if (role == 0) {
        const float fx = (px + 1.0f) * 127.5f;
        const float fy = (py + 1.0f) * 127.5f;
        const float fz = (pz + 1.0f) * 127.5f;
        const float fx0 = floorf(fx), fy0 = floorf(fy), fz0 = floorf(fz);
        const float xd = fx - fx0, yd = fy - fy0, zd = fz - fz0;
        const int ix0 = min(max((int)fx0, 0), 255);
        const int iy0 = min(max((int)fy0, 0), 255);
        const int iz0 = min(max((int)fz0, 0), 255);
        const int ix1 = min(ix0 + 1, 255);
        const int iy1 = min(iy0 + 1, 255);
        const int iz1 = min(iz0 + 1, 255);

        float ret0 = 0.f, c1 = 0.f, c2 = 0.f, c3 = 0.f;
        if (FAST) {
            const unsigned char* dgb = (const unsigned char*)dg;
            const unsigned int vbase = (unsigned int)((ix0 * 65536 + iy0 * 256 + iz0) << 3);
            const unsigned int ox = (unsigned int)((ix1 - ix0) << 19);
            const unsigned int oy = (unsigned int)((iy1 - iy0) << 11);
            const unsigned int oz = (unsigned int)((iz1 - iz0) << 3);
            #pragma unroll
            for (int c = 0; c < 8; ++c) {
                const float wgt = ((c & 4) ? xd : 1.0f - xd) *
                                  ((c & 2) ? yd : 1.0f - yd) *
                                  ((c & 1) ? zd : 1.0f - zd);
                const unsigned int off = vbase + ((c & 4) ? ox : 0u)
                                               + ((c & 2) ? oy : 0u)
                                               + ((c & 1) ? oz : 0u);
                const uint2 w = *(const uint2*)(dgb + off);
                ret0 = fmaf(wgt, bf2f(w.x & 0xffffu), ret0);
                c1   = fmaf(wgt, bf2f(w.x >> 16),     c1);
                c2   = fmaf(wgt, bf2f(w.y & 0xffffu), c2);
                c3   = fmaf(wgt, bf2f(w.y >> 16),     c3);
            }
        } else {
            #pragma unroll
            for (int c = 0; c < 8; ++c) {
                const int i = (c & 4) ? ix1 : ix0;
                const int j = (c & 2) ? iy1 : iy0;
                const int k = (c & 1) ? iz1 : iz0;
                const float wgt = ((c & 4) ? xd : 1.0f - xd) *
                                  ((c & 2) ? yd : 1.0f - yd) *
                                  ((c & 1) ? zd : 1.0f - zd);
                const float v  = gv(grid, i, j, k);
                const float gx = (gv(grid, min(i + 1, 255), j, k) - gv(grid, max(i - 1, 0), j, k)) * 63.75f;
                const float gy = (gv(grid, i, min(j + 1, 255), k) - gv(grid, i, max(j - 1, 0), k)) * 63.75f;
                const float gz = (gv(grid, i, j, min(k + 1, 255)) - gv(grid, i, j, max(k - 1, 0))) * 63.75f;
                ret0 = fmaf(wgt, v,  ret0);
                c1   = fmaf(wgt, gx, c1);
                c2   = fmaf(wgt, gy, c2);
                c3   = fmaf(wgt, gz, c3);
            }
        }
        out[pid] = ret0;
        out[B + pid * 3 + 0] = c1;
        out[B + pid * 3 + 1] = c2;
        out[B + pid * 3 + 2] = c3;
        float* cst = (float*)(fbuf + p2 * FSTRIDE_B + 128);
        cst[0] = c1; cst[1] = c2; cst[2] = c3;
    } else {
        // streamed pos-enc, NATURAL feature order; slots 63..127 zero.
        const float r0 = px * INV2PI, r1 = py * INV2PI, r2 = pz * INV2PI;
        unsigned char* fb = fbuf + p2 * FSTRIDE_B;
        auto slotv = [&](int n) -> float {
            if (n == 0) return px;
            if (n == 1) return py;
            if (n == 2) return pz;
            if (n >= 63) return 0.0f;
            const int m = n - 3, b = m / 6, rem = m % 6, s = rem / 3, d = rem % 3;
            const float rr = (d == 0) ? r0 : (d == 1) ? r1 : r2;
            return vsin(vfract(rr * (float)(1 << b) + (s ? 0.25f : 0.0f)));
        };
        #pragma unroll
        for (int w = 0; w < 8; ++w) {
            int lo = __builtin_amdgcn_cvt_pk_fp8_f32(slotv(8 * w + 0), slotv(8 * w + 1), 0, false);
            lo     = __builtin_amdgcn_cvt_pk_fp8_f32(slotv(8 * w + 2), slotv(8 * w + 3), lo, true);
            int hi = __builtin_amdgcn_cvt_pk_fp8_f32(slotv(8 * w + 4), slotv(8 * w + 5), 0, false);
            hi     = __builtin_amdgcn_cvt_pk_fp8_f32(slotv(8 * w + 6), slotv(8 * w + 7), hi, true);
            uint2 pk; pk.x = (unsigned int)lo; pk.y = (unsigned int)hi;
            *(uint2*)(fb + w * 8) = pk;
        }
        const uint4 z = {0u, 0u, 0u, 0u};
        #pragma unroll
        for (int w = 0; w < 4; ++w) *(uint4*)(fb + 64 + w * 16) = z;
    }
    __builtin_amdgcn_s_barrier();   // phase-align waves (weight L1 reuse)

    // ============ MLP via K=128 MX fp8 MFMA (unit scales) =================
    const int frow = lm * FSTRIDE_B + quad * 32;   // per-lane feature bytes

    v8i actA, actAq;   // pt=0 / pt=1 current activations
    v8i actB, actBq;

    // ---- L0: features (K=128, zero-padded) ----
    {
        const v8i f0 = ldv8(fbuf + frow);
        const v8i f1 = ldv8(fbuf + 16 * FSTRIDE_B + frow);
        #pragma unroll
        for (int ut = 0; ut < 8; ++ut) {
            const v8i w = ldv8(ws8 + L0OFF + (ut * 64 + lane) * 32);
            const f4 bias = *(const f4*)(b0 + ut * 16 + quad * 4);
            f4 a0 = MFMASC(w, f0, bias);
            f4 a1 = MFMASC(w, f1, bias);
            actA[ut]  = (int)pack8(a0);
            actAq[ut] = (int)pack8(a1);
            SCHED_FENCE();
        }
    }

    // ---- L1 (K=128): actA -> actB ----
    #pragma unroll
    for (int ut = 0; ut < 8; ++ut) {
        const v8i w = ldv8(ws8 + L1OFF + (ut * 64 + lane) * 32);
        const f4 bias = *(const f4*)(b1 + ut * 16 + quad * 4);
        f4 a0 = MFMASC(w, actA,  bias);
        f4 a1 = MFMASC(w, actAq, bias);
        actB[ut]  = (int)pack8(a0);
        actBq[ut] = (int)pack8(a1);
        SCHED_FENCE();
    }

    // ---- L2 (K=128): actB -> actA ----
    #pragma unroll
    for (int ut = 0; ut < 8; ++ut) {
        const v8i w = ldv8(ws8 + L2OFF + (ut * 64 + lane) * 32);
        const f4 bias = *(const f4*)(b2 + ut * 16 + quad * 4);
        f4 a0 = MFMASC(w, actB,  bias);
        f4 a1 = MFMASC(w, actBq, bias);
        actA[ut]  = (int)pack8(a0);
        actAq[ut] = (int)pack8(a1);
        SCHED_FENCE();
    }

    // ---- L3 (K=256 = hidden-128 + feature-128): actA,feat -> actB ----
    {
        const v8i f0 = ldv8(fbuf + frow);
        const v8i f1 = ldv8(fbuf + 16 * FSTRIDE_B + frow);
        #pragma unroll
        for (int ut = 0; ut < 8; ++ut) {
            const v8i wh = ldv8(ws8 + L3OFF + ((ut * 2 + 0) * 64 + lane) * 32);
            const v8i wt = ldv8(ws8 + L3OFF + ((ut * 2 + 1) * 64 + lane) * 32);
            const f4 bias = *(const f4*)(b3 + ut * 16 + quad * 4);
            f4 a0 = MFMASC(wh, actA,  bias); a0 = MFMASC(wt, f0, a0);
            f4 a1 = MFMASC(wh, actAq, bias); a1 = MFMASC(wt, f1, a1);
            actB[ut]  = (int)pack8(a0);
            actBq[ut] = (int)pack8(a1);
            SCHED_FENCE();
        }
    }

    // ---- output layer (K=128, N=3 in one 16-tile, wo*2^13) + epilogue ----
    const v8i wout = ldv8(ws8 + OUTOFF + lane * 32);
    const float bo0 = bo[0], bo1 = bo[1], bo2 = bo[2];
    #pragma unroll
    for (int pt = 0; pt < 2; ++pt) {
        f4 acc = {0.f, 0.f, 0.f, 0.f};
        acc = MFMASC(wout, pt ? actBq : actB, acc);

        const int pp = pt * 16 + lm;
        const float* cst = (const float*)(fbuf + pp * FSTRIDE_B + 128);
        const float g1 = cst[0], g2 = cst[1], g3 = cst[2];
        const float r0 = acc[0] * WO_INV + bo0;
        const float r1 = acc[1] * WO_INV + bo1;
        const float r2 = acc[2] * WO_INV + bo2;
        const float theta = sqrtf(fmaf(r0, r0, fmaf(r1, r1, r2 * r2)) + 1e-12f);
        const float it = __builtin_amdgcn_rcpf(theta);
        const float e0 = r0 * it, e1 = r1 * it, e2 = r2 * it;
        const float a = sqrtf(fmaf(g1, g1, fmaf(g2, g2, g3 * g3)) + 1e-12f);
        const float ia = __builtin_amdgcn_rcpf(a);
        const float v0 = g1 * ia, v1 = g2 * ia, v2 = g3 * ia;
        const float rv = theta * INV2PI;
        const float st = vsin(vfract(rv));
        const float ct = vsin(vfract(rv + 0.25f));
        const float cx = e1 * v2 - e2 * v1;
        const float cy = e2 * v0 - e0 * v2;
        const float cz = e0 * v1 - e1 * v0;
        const float om = (1.0f - ct) * (e0 * v0 + e1 * v1 + e2 * v2);
        if (quad == 0) {
            const int pid2 = pbase + pp;
            out[4 * B + pid2 * 3 + 0] = a * (ct * v0 + st * cx + om * e0);
            out[4 * B + pid2 * 3 + 1] = a * (ct * v1 + st * cy + om * e1);
            out[4 * B + pid2 * 3 + 2] = a * (ct * v2 + st * cz + om * e2);
        }
    }
}

extern "C" void kernel_launch(void* const* d_in, const int* in_sizes, int n_in,
                              void* d_out, int out_size, void* d_ws, size_t ws_size,
                              hipStream_t stream)
{
    const float* x    = (const float*)d_in[0];
    const float* grid = (const float*)d_in[1];
    const float* w0   = (const float*)d_in[2];
    const float* b0   = (const float*)d_in[3];
    const float* w1   = (const float*)d_in[4];
    const float* b1   = (const float*)d_in[5];
    const float* w2   = (const float*)d_in[6];
    const float* b2   = (const float*)d_in[7];
    const float* w3   = (const float*)d_in[8];
    const float* b3   = (const float*)d_in[9];
    const float* wo   = (const float*)d_in[10];
    const float* bo   = (const float*)d_in[11];
    float* out = (float*)d_out;
    unsigned char* ws8 = (unsigned char*)d_ws;
    unsigned short* dg = (unsigned short*)d_ws + DG_OFF_SH;

    const int B = in_sizes[0] / 3;        // 1,048,576
    const int fast = (ws_size >= WS_NEED) ? 1 : 0;
    const int nprep = fast ? (SWZ_BLOCKS + DG_BLOCKS) : SWZ_BLOCKS;
    prep<<<nprep, 256, 0, stream>>>(grid, w0, w1, w2, w3, wo, ws8, dg, fast);
    if (fast)
        voxmlp<true><<<B / 128, 256, 0, stream>>>(x, grid, ws8, dg, b0, b1, b2, b3, bo, out, B);
    else
        voxmlp<false><<<B / 128, 256, 0, stream>>>(x, grid, ws8, dg, b0, b1, b2, b3, bo, out, B);
}